// Round 1
// baseline (316.328 us; speedup 1.0000x reference)
//
#include <hip/hip_runtime.h>

#define N_SEQ 16384
#define T 16
#define E 30
#define H 50
#define G4 200   // 4*H
#define NS 8     // sequences per block
#define VOCAB 100

// tbl[v][g] = dot(emb[v], w_ih[g]) + b_ih[g] + b_hh[g]
__global__ void build_tbl(const float* __restrict__ emb,
                          const float* __restrict__ w_ih,
                          const float* __restrict__ b_ih,
                          const float* __restrict__ b_hh,
                          float* __restrict__ tbl) {
    int idx = blockIdx.x * blockDim.x + threadIdx.x;
    if (idx >= VOCAB * G4) return;
    int v = idx / G4, g = idx % G4;
    float s = b_ih[g] + b_hh[g];
    const float* er = emb + v * E;
    const float* wr = w_ih + g * E;
#pragma unroll
    for (int e = 0; e < E; ++e) s += er[e] * wr[e];
    tbl[idx] = s;
}

__device__ __forceinline__ float sigm(float x) { return 1.0f / (1.0f + __expf(-x)); }
__device__ __forceinline__ float ftanh(float x) {
    float e = __expf(2.0f * x);
    return (e - 1.0f) / (e + 1.0f);
}

__global__ __launch_bounds__(256) void lstm_kernel(
    const int* __restrict__ ids,     // [N_SEQ, T]
    const float* __restrict__ tbl,   // [2][VOCAB][G4]  (fwd then rev)
    const float* __restrict__ whh_f, // [G4][H]
    const float* __restrict__ whh_r, // [G4][H]
    float* __restrict__ out)         // [N_SEQ, 2*H]
{
    __shared__ __align__(16) float s_h[NS][52];   // h state, padded stride
    __shared__ float s_g[NS][G4];                 // gate pre-activations
    __shared__ int s_ids[NS][T];
    __shared__ int s_capt[NS];

    const int tid = threadIdx.x;
    const int nb = N_SEQ / NS; // 2048 blocks per direction
    const int b = blockIdx.x;
    const int dir = (b >= nb) ? 1 : 0;
    const int s0 = (dir ? (b - nb) : b) * NS;

    const float* __restrict__ whh = dir ? whh_r : whh_f;
    const float* __restrict__ tb  = tbl + dir * (VOCAB * G4);

    // load ids for this block's sequences
    if (tid < NS * T) {
        int s = tid / T, t = tid % T;
        s_ids[s][t] = ids[(s0 + s) * T + t];
    }
    // each gate thread owns one weight row in registers (zero-padded to 52)
    float w[52];
    if (tid < G4) {
#pragma unroll
        for (int k = 0; k < H; ++k) w[k] = whh[tid * H + k];
        w[50] = 0.f; w[51] = 0.f;
    }
    // init h = 0
    for (int i = tid; i < NS * 52; i += 256) ((float*)s_h)[i] = 0.f;
    __syncthreads();
    // ragged lengths -> forward capture step
    if (tid < NS) {
        int len = 0;
#pragma unroll
        for (int t = 0; t < T; ++t) len += (s_ids[tid][t] != 0) ? 1 : 0;
        s_capt[tid] = (len > 1) ? (len - 1) : 0;
    }

    // phase-2 ownership: tasks u = s*H + j, u in [0, NS*H=400)
    const int u0 = tid;          // always valid (tid < 256 < 400)
    const int u1 = tid + 256;    // valid if tid < 144
    const int sa = u0 / H, ja = u0 % H;
    const int sb = u1 / H, jb = u1 % H;
    float c0 = 0.f, c1 = 0.f;

    for (int t = 0; t < T; ++t) {
        __syncthreads(); // s_h (and s_capt at t=0) ready
        const int tt = dir ? (T - 1 - t) : t;

        // ---- phase 1: gates[s][g] = tbl[id][g] + dot(h[s], w_hh[g]) ----
        if (tid < G4) {
            float acc[NS];
#pragma unroll
            for (int s = 0; s < NS; ++s)
                acc[s] = tb[s_ids[s][tt] * G4 + tid];   // coalesced row gather
#pragma unroll
            for (int k = 0; k < 13; ++k) {
#pragma unroll
                for (int s = 0; s < NS; ++s) {
                    float4 hv = *(const float4*)&s_h[s][k * 4]; // broadcast read
                    acc[s] = fmaf(hv.x, w[k*4+0], acc[s]);
                    acc[s] = fmaf(hv.y, w[k*4+1], acc[s]);
                    acc[s] = fmaf(hv.z, w[k*4+2], acc[s]);
                    acc[s] = fmaf(hv.w, w[k*4+3], acc[s]);
                }
            }
#pragma unroll
            for (int s = 0; s < NS; ++s) s_g[s][tid] = acc[s];
        }
        __syncthreads();

        // ---- phase 2: per hidden unit c/h update ----
        {
            float gi = s_g[sa][ja], gf = s_g[sa][ja + H];
            float gg = s_g[sa][ja + 2 * H], go = s_g[sa][ja + 3 * H];
            float i_ = sigm(gi), f_ = sigm(gf), g_ = ftanh(gg), o_ = sigm(go);
            c0 = f_ * c0 + i_ * g_;
            float h = o_ * ftanh(c0);
            s_h[sa][ja] = h;
            if (dir == 0) {
                if (t == s_capt[sa]) out[(s0 + sa) * (2 * H) + ja] = h;
            } else {
                if (t == T - 1)      out[(s0 + sa) * (2 * H) + H + ja] = h;
            }
        }
        if (u1 < NS * H) {
            float gi = s_g[sb][jb], gf = s_g[sb][jb + H];
            float gg = s_g[sb][jb + 2 * H], go = s_g[sb][jb + 3 * H];
            float i_ = sigm(gi), f_ = sigm(gf), g_ = ftanh(gg), o_ = sigm(go);
            c1 = f_ * c1 + i_ * g_;
            float h = o_ * ftanh(c1);
            s_h[sb][jb] = h;
            if (dir == 0) {
                if (t == s_capt[sb]) out[(s0 + sb) * (2 * H) + jb] = h;
            } else {
                if (t == T - 1)      out[(s0 + sb) * (2 * H) + H + jb] = h;
            }
        }
    }
}

extern "C" void kernel_launch(void* const* d_in, const int* in_sizes, int n_in,
                              void* d_out, int out_size, void* d_ws, size_t ws_size,
                              hipStream_t stream) {
    const int*   char_ids = (const int*)d_in[0];
    const float* emb      = (const float*)d_in[1];
    const float* w_ih_f   = (const float*)d_in[2];
    const float* w_hh_f   = (const float*)d_in[3];
    const float* b_ih_f   = (const float*)d_in[4];
    const float* b_hh_f   = (const float*)d_in[5];
    const float* w_ih_r   = (const float*)d_in[6];
    const float* w_hh_r   = (const float*)d_in[7];
    const float* b_ih_r   = (const float*)d_in[8];
    const float* b_hh_r   = (const float*)d_in[9];
    float* out = (float*)d_out;
    float* tbl = (float*)d_ws; // [2][VOCAB][G4] = 160 KB

    const int nt = VOCAB * G4; // 20000
    build_tbl<<<(nt + 255) / 256, 256, 0, stream>>>(emb, w_ih_f, b_ih_f, b_hh_f, tbl);
    build_tbl<<<(nt + 255) / 256, 256, 0, stream>>>(emb, w_ih_r, b_ih_r, b_hh_r, tbl + nt);
    lstm_kernel<<<2 * (N_SEQ / NS), 256, 0, stream>>>(char_ids, tbl, w_hh_f, w_hh_r, out);
}

// Round 2
// 311.150 us; speedup vs baseline: 1.0166x; 1.0166x over previous
//
#include <hip/hip_runtime.h>

#define N_SEQ 16384
#define T 16
#define E 30
#define H 50
#define G4 200   // 4*H
#define NS 8     // sequences per block
#define VOCAB 100

// tbl[v][g] = dot(emb[v], w_ih[g]) + b_ih[g] + b_hh[g]
__global__ void build_tbl(const float* __restrict__ emb,
                          const float* __restrict__ w_ih,
                          const float* __restrict__ b_ih,
                          const float* __restrict__ b_hh,
                          float* __restrict__ tbl) {
    int idx = blockIdx.x * blockDim.x + threadIdx.x;
    if (idx >= VOCAB * G4) return;
    int v = idx / G4, g = idx % G4;
    float s = b_ih[g] + b_hh[g];
    const float* er = emb + v * E;
    const float* wr = w_ih + g * E;
#pragma unroll
    for (int e = 0; e < E; ++e) s += er[e] * wr[e];
    tbl[idx] = s;
}

__device__ __forceinline__ float sigm(float x) { return 1.0f / (1.0f + __expf(-x)); }
__device__ __forceinline__ float ftanh(float x) {
    float e = __expf(2.0f * x);
    return (e - 1.0f) / (e + 1.0f);
}

// __launch_bounds__(256, 1): allow the allocator up to 256 VGPRs so the
// 52-float weight row stays register-resident (R1: compiler clamped to 52
// VGPRs for 8 waves/SIMD and demoted w[] -> load-per-FMA inner loop).
__global__ __launch_bounds__(256, 1) void lstm_kernel(
    const int* __restrict__ ids,     // [N_SEQ, T]
    const float* __restrict__ tbl,   // [2][VOCAB][G4]  (fwd then rev)
    const float* __restrict__ whh_f, // [G4][H]
    const float* __restrict__ whh_r, // [G4][H]
    float* __restrict__ out)         // [N_SEQ, 2*H]
{
    __shared__ __align__(16) float s_h[NS][52];   // h state, padded stride
    __shared__ float s_g[NS][G4];                 // gate pre-activations
    __shared__ int s_ids[NS][T];
    __shared__ int s_capt[NS];

    const int tid = threadIdx.x;
    const int nb = N_SEQ / NS; // 2048 blocks per direction
    const int b = blockIdx.x;
    const int dir = (b >= nb) ? 1 : 0;
    const int s0 = (dir ? (b - nb) : b) * NS;

    const float* __restrict__ whh = dir ? whh_r : whh_f;
    const float* __restrict__ tb  = tbl + dir * (VOCAB * G4);

    // load ids for this block's sequences
    if (tid < NS * T) {
        int s = tid / T, t = tid % T;
        s_ids[s][t] = ids[(s0 + s) * T + t];
    }
    // each gate thread owns one weight row in registers (zero-padded to 52);
    // load unconditionally (clamped row) so liveness isn't tangled in a branch
    const int wrow = (tid < G4) ? tid : (G4 - 1);
    float w[52];
#pragma unroll
    for (int k = 0; k < H; ++k) w[k] = whh[wrow * H + k];
    w[50] = 0.f; w[51] = 0.f;

    // init h = 0
    for (int i = tid; i < NS * 52; i += 256) ((float*)s_h)[i] = 0.f;
    __syncthreads();
    // ragged lengths -> forward capture step
    if (tid < NS) {
        int len = 0;
#pragma unroll
        for (int t = 0; t < T; ++t) len += (s_ids[tid][t] != 0) ? 1 : 0;
        s_capt[tid] = (len > 1) ? (len - 1) : 0;
    }

    // phase-2 ownership: tasks u = s*H + j, u in [0, NS*H=400)
    const int u0 = tid;          // always valid (tid < 256 < 400)
    const int u1 = tid + 256;    // valid if tid < 144
    const int sa = u0 / H, ja = u0 % H;
    const int sb = u1 / H, jb = u1 % H;
    float c0 = 0.f, c1 = 0.f;

    for (int t = 0; t < T; ++t) {
        __syncthreads(); // s_h (and s_capt at t=0) ready
        const int tt = dir ? (T - 1 - t) : t;

        // ---- phase 1: gates[s][g] = tbl[id][g] + dot(h[s], w_hh[g]) ----
        if (tid < G4) {
            float acc[NS];
#pragma unroll
            for (int s = 0; s < NS; ++s)
                acc[s] = tb[s_ids[s][tt] * G4 + tid];   // coalesced row gather
#pragma unroll
            for (int k = 0; k < 13; ++k) {
#pragma unroll
                for (int s = 0; s < NS; ++s) {
                    float4 hv = *(const float4*)&s_h[s][k * 4]; // broadcast read
                    acc[s] = fmaf(hv.x, w[k*4+0], acc[s]);
                    acc[s] = fmaf(hv.y, w[k*4+1], acc[s]);
                    acc[s] = fmaf(hv.z, w[k*4+2], acc[s]);
                    acc[s] = fmaf(hv.w, w[k*4+3], acc[s]);
                }
            }
#pragma unroll
            for (int s = 0; s < NS; ++s) s_g[s][tid] = acc[s];
        }
        __syncthreads();

        // ---- phase 2: per hidden unit c/h update ----
        {
            float gi = s_g[sa][ja], gf = s_g[sa][ja + H];
            float gg = s_g[sa][ja + 2 * H], go = s_g[sa][ja + 3 * H];
            float i_ = sigm(gi), f_ = sigm(gf), g_ = ftanh(gg), o_ = sigm(go);
            c0 = f_ * c0 + i_ * g_;
            float h = o_ * ftanh(c0);
            s_h[sa][ja] = h;
            if (dir == 0) {
                if (t == s_capt[sa]) out[(s0 + sa) * (2 * H) + ja] = h;
            } else {
                if (t == T - 1)      out[(s0 + sa) * (2 * H) + H + ja] = h;
            }
        }
        if (u1 < NS * H) {
            float gi = s_g[sb][jb], gf = s_g[sb][jb + H];
            float gg = s_g[sb][jb + 2 * H], go = s_g[sb][jb + 3 * H];
            float i_ = sigm(gi), f_ = sigm(gf), g_ = ftanh(gg), o_ = sigm(go);
            c1 = f_ * c1 + i_ * g_;
            float h = o_ * ftanh(c1);
            s_h[sb][jb] = h;
            if (dir == 0) {
                if (t == s_capt[sb]) out[(s0 + sb) * (2 * H) + jb] = h;
            } else {
                if (t == T - 1)      out[(s0 + sb) * (2 * H) + H + jb] = h;
            }
        }
    }
}

extern "C" void kernel_launch(void* const* d_in, const int* in_sizes, int n_in,
                              void* d_out, int out_size, void* d_ws, size_t ws_size,
                              hipStream_t stream) {
    const int*   char_ids = (const int*)d_in[0];
    const float* emb      = (const float*)d_in[1];
    const float* w_ih_f   = (const float*)d_in[2];
    const float* w_hh_f   = (const float*)d_in[3];
    const float* b_ih_f   = (const float*)d_in[4];
    const float* b_hh_f   = (const float*)d_in[5];
    const float* w_ih_r   = (const float*)d_in[6];
    const float* w_hh_r   = (const float*)d_in[7];
    const float* b_ih_r   = (const float*)d_in[8];
    const float* b_hh_r   = (const float*)d_in[9];
    float* out = (float*)d_out;
    float* tbl = (float*)d_ws; // [2][VOCAB][G4] = 160 KB

    const int nt = VOCAB * G4; // 20000
    build_tbl<<<(nt + 255) / 256, 256, 0, stream>>>(emb, w_ih_f, b_ih_f, b_hh_f, tbl);
    build_tbl<<<(nt + 255) / 256, 256, 0, stream>>>(emb, w_ih_r, b_ih_r, b_hh_r, tbl + nt);
    lstm_kernel<<<2 * (N_SEQ / NS), 256, 0, stream>>>(char_ids, tbl, w_hh_f, w_hh_r, out);
}